// Round 2
// baseline (1063.287 us; speedup 1.0000x reference)
//
#include <hip/hip_runtime.h>

// GQA (B=2,S=2048,E=2048,H=32,G=8,D=64), softmax over HEAD axis.
// R2: attn restructured — scores never touch LDS (exp in regs, cross-wave
// head-sum via ds_add_f32 into 2KB buffer), V transposed via registers with
// swizzled b32 writes, P overlaid on dead K region. LDS 133->67.6 KB.

typedef unsigned short u16;
typedef unsigned int u32;
typedef __attribute__((ext_vector_type(8))) __bf16 bf16x8;
typedef __attribute__((ext_vector_type(4))) float f32x4;
typedef __attribute__((ext_vector_type(4))) float float4_t;

#define GLD16(ldsp, gp)                                                  \
  __builtin_amdgcn_global_load_lds(                                      \
      (__attribute__((address_space(1))) void*)(void*)(gp),              \
      (__attribute__((address_space(3))) void*)(void*)(ldsp), 16, 0, 0)

static __device__ __forceinline__ u16 f2bf(float f) {
  union { float f; u32 u; } v; v.f = f;
  u32 u = v.u;
  u32 r = (u + 0x7fffu + ((u >> 16) & 1u)) >> 16;  // RNE
  return (u16)r;
}

static __device__ __forceinline__ bf16x8 ld8(const u16* p) {
  return *(const bf16x8*)p;
}

// ---------------- fp32 -> bf16 ----------------
__global__ void cvt_bf16(const float* __restrict__ in, u16* __restrict__ out, int n8) {
  int i = blockIdx.x * blockDim.x + threadIdx.x;
  int stride = gridDim.x * blockDim.x;
  for (; i < n8; i += stride) {
    const float4_t* p = (const float4_t*)in + (size_t)i * 2;
    float4_t a = p[0], b = p[1];
    u32 w0 = (u32)f2bf(a[0]) | ((u32)f2bf(a[1]) << 16);
    u32 w1 = (u32)f2bf(a[2]) | ((u32)f2bf(a[3]) << 16);
    u32 w2 = (u32)f2bf(b[0]) | ((u32)f2bf(b[1]) << 16);
    u32 w3 = (u32)f2bf(b[2]) | ((u32)f2bf(b[3]) << 16);
    *(uint4*)(out + (size_t)i * 8) = make_uint4(w0, w1, w2, w3);
  }
}

// ---------------- GEMM: C[M,N] = A[M,K] @ W[N,K]^T + bias ----------------
template <bool OUT_BF16>
__global__ __launch_bounds__(256, 2)
void gemm_bt(const u16* __restrict__ A, const u16* __restrict__ Bw,
             const float* __restrict__ bias,
             u16* __restrict__ Cb, float* __restrict__ Cf, int N) {
  constexpr int K = 2048;
  __shared__ u16 As[128 * 32];
  __shared__ u16 Bs[128 * 32];
  const int tid = threadIdx.x;
  const int lane = tid & 63;
  const int w = tid >> 6;
  const int m0 = blockIdx.y * 128;
  const int n0 = blockIdx.x * 128;
  const int wr = (w >> 1) * 64, wc = (w & 1) * 64;
  const int r15 = lane & 15, kq = lane >> 4;

  f32x4 acc[4][4] = {};

  for (int k0 = 0; k0 < K; k0 += 32) {
#pragma unroll
    for (int i = 0; i < 2; ++i) {
      int c = i * 256 + tid;
      int r = c >> 2, ch = c & 3;
      int sc = (ch ^ (r & 3)) * 8;
      GLD16(&As[c * 8], &A[(size_t)(m0 + r) * K + k0 + sc]);
      GLD16(&Bs[c * 8], &Bw[(size_t)(n0 + r) * K + k0 + sc]);
    }
    __syncthreads();
    bf16x8 af[4], bfr[4];
#pragma unroll
    for (int mt = 0; mt < 4; ++mt) {
      int r = wr + mt * 16 + r15;
      af[mt] = ld8(&As[r * 32 + ((kq ^ (r15 & 3)) * 8)]);
    }
#pragma unroll
    for (int nt = 0; nt < 4; ++nt) {
      int r = wc + nt * 16 + r15;
      bfr[nt] = ld8(&Bs[r * 32 + ((kq ^ (r15 & 3)) * 8)]);
    }
#pragma unroll
    for (int mt = 0; mt < 4; ++mt)
#pragma unroll
      for (int nt = 0; nt < 4; ++nt)
        acc[mt][nt] = __builtin_amdgcn_mfma_f32_16x16x32_bf16(af[mt], bfr[nt], acc[mt][nt], 0, 0, 0);
    __syncthreads();
  }
  const int rb = kq * 4;
#pragma unroll
  for (int mt = 0; mt < 4; ++mt) {
#pragma unroll
    for (int nt = 0; nt < 4; ++nt) {
      int col = n0 + wc + nt * 16 + r15;
      float bv = bias[col];
#pragma unroll
      for (int r = 0; r < 4; ++r) {
        int row = m0 + wr + mt * 16 + rb + r;
        float v = acc[mt][nt][r] + bv;
        if constexpr (OUT_BF16) Cb[(size_t)row * N + col] = f2bf(v);
        else                    Cf[(size_t)row * N + col] = v;
      }
    }
  }
}

// ---------------- fused attention (R2) ----------------
// Block = 1024 thr (16 waves), (b, 16-row q-tile). Wave w owns heads 2w,2w+1.
// Per 32-key tile: stage K (gload_lds, src-swizzle) + V (reg transpose,
// swizzled b32 writes) | B1 | QK^T->regs, exp in regs, 4h partials via
// ds_add_f32 into Ssum[16q][33] | B2 | P = e*rcp(sum) -> bf16 into Kl region
// | B3 | PV (b128 reads, swizzled) + zero Ssum | B4.
__global__ __launch_bounds__(1024, 4)
void attn_fused(const u16* __restrict__ Q, const u16* __restrict__ Kg,
                const u16* __restrict__ Vg, u16* __restrict__ O) {
  __shared__ u16 Kl[16384];    // K tile [32][512] (src-swz); later P [32h][16q][32k] (chunk-swz)
  __shared__ u16 Vl[16384];    // V^T [8g][64d][32kk], kk-field xor ((d&3)<<3 | ((d>>3)&1)<<4)
  __shared__ float Ssum[528];  // [16q][33] head-sum accumulator

  const int tid = threadIdx.x;
  const int lane = tid & 63, w = tid >> 6;
  const int bid = blockIdx.x;
  // XCD-contiguous: batch b pinned to 4 XCDs -> its 2MB K/V stays in those L2s
  const int b = (bid & 7) >> 2;
  const int q0 = (((bid & 3) << 5) + (bid >> 3)) << 4;
  const int r15 = lane & 15, kq = lane >> 4;
  const int h0 = w * 2;

  // Q fragments (A-operand): lane r15 <-> q-row, elems = d
  bf16x8 qf[2][2];
#pragma unroll
  for (int hh = 0; hh < 2; ++hh)
#pragma unroll
    for (int t = 0; t < 2; ++t)
      qf[hh][t] = ld8(&Q[(size_t)(b * 2048 + q0 + r15) * 2048 + (h0 + hh) * 64 + t * 32 + kq * 8]);

  f32x4 acc[2][4] = {};

  // V staging constants: thread -> kk-pair {2*va, 2*va+1}, 16B chunk vp
  const int va = tid & 15;
  const int vp = (tid >> 4) & 63;
  const int vg = vp >> 3, vd0 = (vp & 7) * 8;

  if (tid < 264) ((float2*)Ssum)[tid] = make_float2(0.f, 0.f);

  for (int k0 = 0; k0 < 2048; k0 += 32) {
    // ---- stage K: linear LDS dest, swizzle via global source ----
#pragma unroll
    for (int i = 0; i < 2; ++i) {
      int c = i * 1024 + tid;
      int kk = c >> 6, ch = c & 63;
      GLD16(&Kl[c * 8], &Kg[(size_t)(b * 2048 + k0 + kk) * 512 + ((ch ^ (kk & 7)) * 8)]);
    }
    // ---- stage V: load kk-pair, in-reg transpose, swizzled b32 writes ----
    {
      bf16x8 v0 = ld8(&Vg[(size_t)(b * 2048 + k0 + 2 * va + 0) * 512 + vp * 8]);
      bf16x8 v1 = ld8(&Vg[(size_t)(b * 2048 + k0 + 2 * va + 1) * 512 + vp * 8]);
      const u32* w0 = (const u32*)&v0;
      const u32* w1 = (const u32*)&v1;
#pragma unroll
      for (int j = 0; j < 8; ++j) {
        u32 pk = __builtin_amdgcn_perm(w1[j >> 1], w0[j >> 1],
                                       (j & 1) ? 0x07060302u : 0x05040100u);
        int row = vd0 + j;
        int xo = ((j & 3) << 3) | ((vp & 1) << 4);  // row&3==j&3, (row>>3)&1==vp&1
        *(u32*)&Vl[vg * 2048 + row * 32 + ((2 * va) ^ xo)] = pk;
      }
    }
    __syncthreads();  // B1

    // ---- QK^T -> regs, exp, head-partial sums ----
    float part[2][4] = {};
    u32 ep[2][2][2];
#pragma unroll
    for (int hh = 0; hh < 2; ++hh) {
      const int g = (h0 + hh) & 7;
      f32x4 sv[2] = {};
#pragma unroll
      for (int ko = 0; ko < 2; ++ko)
#pragma unroll
        for (int t = 0; t < 2; ++t) {
          int u = g * 8 + t * 4 + kq;
          bf16x8 bk = ld8(&Kl[(ko * 16 + r15) * 512 + ((u ^ (r15 & 7)) * 8)]);
          sv[ko] = __builtin_amdgcn_mfma_f32_16x16x32_bf16(qf[hh][t], bk, sv[ko], 0, 0, 0);
        }
#pragma unroll
      for (int ko = 0; ko < 2; ++ko) {
        float e0 = __expf(sv[ko][0] * 0.125f);
        float e1 = __expf(sv[ko][1] * 0.125f);
        float e2 = __expf(sv[ko][2] * 0.125f);
        float e3 = __expf(sv[ko][3] * 0.125f);
        part[ko][0] += e0; part[ko][1] += e1; part[ko][2] += e2; part[ko][3] += e3;
        // pack e (truncate to bf16): [e_lo | e_hi<<16]
        ep[hh][ko][0] = __builtin_amdgcn_perm(__float_as_uint(e1), __float_as_uint(e0), 0x07060302u);
        ep[hh][ko][1] = __builtin_amdgcn_perm(__float_as_uint(e3), __float_as_uint(e2), 0x07060302u);
      }
    }
#pragma unroll
    for (int ko = 0; ko < 2; ++ko)
#pragma unroll
      for (int r = 0; r < 4; ++r)
        atomicAdd(&Ssum[(kq * 4 + r) * 33 + ko * 16 + r15], part[ko][r]);
    __syncthreads();  // B2

    // ---- P = e * rcp(sum) -> bf16 into Kl (K dead) ----
    float rsv[2][4];
#pragma unroll
    for (int ko = 0; ko < 2; ++ko)
#pragma unroll
      for (int r = 0; r < 4; ++r)
        rsv[ko][r] = __builtin_amdgcn_rcpf(Ssum[(kq * 4 + r) * 33 + ko * 16 + r15]);
#pragma unroll
    for (int hh = 0; hh < 2; ++hh) {
      const int bh = (h0 + hh) * 16;
#pragma unroll
      for (int ko = 0; ko < 2; ++ko) {
        const u32 lo = ep[hh][ko][0], hi = ep[hh][ko][1];
        const int k = ko * 16 + r15;
        float p0 = __uint_as_float(lo << 16)         * rsv[ko][0];
        float p1 = __uint_as_float(lo & 0xffff0000u) * rsv[ko][1];
        float p2 = __uint_as_float(hi << 16)         * rsv[ko][2];
        float p3 = __uint_as_float(hi & 0xffff0000u) * rsv[ko][3];
        const int qb = kq * 4;
        Kl[(bh + qb + 0) * 32 + (k ^ (((0 ^ kq) & 3) << 3))] = (u16)(__float_as_uint(p0) >> 16);
        Kl[(bh + qb + 1) * 32 + (k ^ (((1 ^ kq) & 3) << 3))] = (u16)(__float_as_uint(p1) >> 16);
        Kl[(bh + qb + 2) * 32 + (k ^ (((2 ^ kq) & 3) << 3))] = (u16)(__float_as_uint(p2) >> 16);
        Kl[(bh + qb + 3) * 32 + (k ^ (((3 ^ kq) & 3) << 3))] = (u16)(__float_as_uint(p3) >> 16);
      }
    }
    __syncthreads();  // B3

    // ---- PV + re-zero Ssum for next tile ----
    if (tid < 264) ((float2*)Ssum)[tid] = make_float2(0.f, 0.f);
    const int qxr = (r15 ^ (r15 >> 2)) & 3;
#pragma unroll
    for (int hh = 0; hh < 2; ++hh) {
      const int h = h0 + hh, g = h & 7;
      bf16x8 pa = ld8(&Kl[(h * 16 + r15) * 32 + ((kq ^ qxr) * 8)]);
#pragma unroll
      for (int nt = 0; nt < 4; ++nt) {
        int d = nt * 16 + r15;
        int xo = ((d & 3) << 3) | (((d >> 3) & 1) << 4);
        bf16x8 vb = ld8(&Vl[g * 2048 + d * 32 + ((kq * 8) ^ xo)]);
        acc[hh][nt] = __builtin_amdgcn_mfma_f32_16x16x32_bf16(pa, vb, acc[hh][nt], 0, 0, 0);
      }
    }
    __syncthreads();  // B4
  }

  // ---- epilogue ----
#pragma unroll
  for (int hh = 0; hh < 2; ++hh)
#pragma unroll
    for (int nt = 0; nt < 4; ++nt)
#pragma unroll
      for (int r = 0; r < 4; ++r) {
        int row = q0 + kq * 4 + r;
        O[(size_t)(b * 2048 + row) * 2048 + (h0 + hh) * 64 + nt * 16 + r15] =
            f2bf(acc[hh][nt][r]);
      }
}

// ---------------- launcher ----------------
extern "C" void kernel_launch(void* const* d_in, const int* in_sizes, int n_in,
                              void* d_out, int out_size, void* d_ws, size_t ws_size,
                              hipStream_t stream) {
  (void)in_sizes; (void)n_in; (void)out_size; (void)ws_size;
  const float* x    = (const float*)d_in[0];
  const float* wq_w = (const float*)d_in[1];
  const float* wq_b = (const float*)d_in[2];
  const float* wk_w = (const float*)d_in[3];
  const float* wk_b = (const float*)d_in[4];
  const float* wv_w = (const float*)d_in[5];
  const float* wv_b = (const float*)d_in[6];
  const float* wo_w = (const float*)d_in[7];
  const float* wo_b = (const float*)d_in[8];
  float* out = (float*)d_out;

  char* p = (char*)d_ws;
  u16* xb  = (u16*)p; p += (size_t)4096 * 2048 * 2;
  u16* wqb = (u16*)p; p += (size_t)2048 * 2048 * 2;
  u16* wkb = (u16*)p; p += (size_t)512 * 2048 * 2;
  u16* wvb = (u16*)p; p += (size_t)512 * 2048 * 2;
  u16* wob = (u16*)p; p += (size_t)2048 * 2048 * 2;
  u16* Qb  = (u16*)p; p += (size_t)4096 * 2048 * 2;
  u16* Kb  = (u16*)p; p += (size_t)4096 * 512 * 2;
  u16* Vb  = (u16*)p; p += (size_t)4096 * 512 * 2;
  u16* Ob  = (u16*)p; p += (size_t)4096 * 2048 * 2;

  auto cvt = [&](const float* in, u16* o, int n) {
    int n8 = n / 8;
    int grid = (n8 + 255) / 256; if (grid > 2048) grid = 2048;
    hipLaunchKernelGGL(cvt_bf16, dim3(grid), dim3(256), 0, stream, in, o, n8);
  };
  cvt(x, xb, 4096 * 2048);
  cvt(wq_w, wqb, 2048 * 2048);
  cvt(wk_w, wkb, 512 * 2048);
  cvt(wv_w, wvb, 512 * 2048);
  cvt(wo_w, wob, 2048 * 2048);

  hipLaunchKernelGGL((gemm_bt<true>),  dim3(16, 32), dim3(256), 0, stream,
                     xb, wqb, wq_b, Qb, (float*)nullptr, 2048);
  hipLaunchKernelGGL((gemm_bt<true>),  dim3(4, 32),  dim3(256), 0, stream,
                     xb, wkb, wk_b, Kb, (float*)nullptr, 512);
  hipLaunchKernelGGL((gemm_bt<true>),  dim3(4, 32),  dim3(256), 0, stream,
                     xb, wvb, wv_b, Vb, (float*)nullptr, 512);

  hipLaunchKernelGGL(attn_fused, dim3(256), dim3(1024), 0, stream, Qb, Kb, Vb, Ob);

  hipLaunchKernelGGL((gemm_bt<false>), dim3(16, 32), dim3(256), 0, stream,
                     Ob, wob, wo_b, (u16*)nullptr, out, 2048);
}

// Round 3
// 462.057 us; speedup vs baseline: 2.3012x; 2.3012x over previous
//
#include <hip/hip_runtime.h>

// GQA (B=2,S=2048,E=2048,H=32,G=8,D=64), softmax over HEAD axis.
// R3: attn fully restructured.
//  - A-tile rows = 4 heads sharing kv-group g x 4 q-rows -> head-sum is
//    2x shfl_xor intra-wave; only 8-way cross-g sum via LDS slab (no atomics).
//  - No K/V LDS staging: K row-major + pre-transposed Vt read direct from
//    global (L2); each block reads K[b]/Vt[b] exactly once (~1GB L2 total).
//  - P through LDS in padded [row][40] layout: b128 reads, ~2-way writes.
//  - 16 waves (8g x 2half), grid 256 (1 block/CU), 3 barriers/tile.
//  - Vt produced by V-proj GEMM with LDS-transpose epilogue.

typedef unsigned short u16;
typedef unsigned int u32;
typedef __attribute__((ext_vector_type(8))) __bf16 bf16x8;
typedef __attribute__((ext_vector_type(4))) float f32x4;
typedef __attribute__((ext_vector_type(4))) float float4_t;

#define GLD16(ldsp, gp)                                                  \
  __builtin_amdgcn_global_load_lds(                                      \
      (__attribute__((address_space(1))) void*)(void*)(gp),              \
      (__attribute__((address_space(3))) void*)(void*)(ldsp), 16, 0, 0)

static __device__ __forceinline__ u16 f2bf(float f) {
  union { float f; u32 u; } v; v.f = f;
  u32 u = v.u;
  u32 r = (u + 0x7fffu + ((u >> 16) & 1u)) >> 16;  // RNE
  return (u16)r;
}

static __device__ __forceinline__ bf16x8 ld8(const u16* p) {
  return *(const bf16x8*)p;
}

// ---------------- fp32 -> bf16 ----------------
__global__ void cvt_bf16(const float* __restrict__ in, u16* __restrict__ out, int n8) {
  int i = blockIdx.x * blockDim.x + threadIdx.x;
  int stride = gridDim.x * blockDim.x;
  for (; i < n8; i += stride) {
    const float4_t* p = (const float4_t*)in + (size_t)i * 2;
    float4_t a = p[0], b = p[1];
    u32 w0 = (u32)f2bf(a[0]) | ((u32)f2bf(a[1]) << 16);
    u32 w1 = (u32)f2bf(a[2]) | ((u32)f2bf(a[3]) << 16);
    u32 w2 = (u32)f2bf(b[0]) | ((u32)f2bf(b[1]) << 16);
    u32 w3 = (u32)f2bf(b[2]) | ((u32)f2bf(b[3]) << 16);
    *(uint4*)(out + (size_t)i * 8) = make_uint4(w0, w1, w2, w3);
  }
}

// ---------------- GEMM: C[M,N] = A[M,K] @ W[N,K]^T + bias ----------------
// MODE 0: bf16 out row-major; 1: f32 out row-major; 2: bf16 out transposed
// per-batch (Vt[b*512 + col][s]) via LDS-transpose epilogue.
template <int MODE>
__global__ __launch_bounds__(256, 2)
void gemm_bt(const u16* __restrict__ A, const u16* __restrict__ Bw,
             const float* __restrict__ bias,
             u16* __restrict__ Cb, float* __restrict__ Cf, int N) {
  constexpr int K = 2048;
  constexpr int SHSZ = (MODE == 2) ? (128 * 136) : 8192;
  __shared__ u16 sh[SHSZ];
  u16* As = sh;
  u16* Bs = sh + 4096;
  const int tid = threadIdx.x;
  const int lane = tid & 63;
  const int w = tid >> 6;
  const int m0 = blockIdx.y * 128;
  const int n0 = blockIdx.x * 128;
  const int wr = (w >> 1) * 64, wc = (w & 1) * 64;
  const int r15 = lane & 15, kq = lane >> 4;

  f32x4 acc[4][4] = {};

  for (int k0 = 0; k0 < K; k0 += 32) {
#pragma unroll
    for (int i = 0; i < 2; ++i) {
      int c = i * 256 + tid;
      int r = c >> 2, ch = c & 3;
      int sc = (ch ^ (r & 3)) * 8;
      GLD16(&As[c * 8], &A[(size_t)(m0 + r) * K + k0 + sc]);
      GLD16(&Bs[c * 8], &Bw[(size_t)(n0 + r) * K + k0 + sc]);
    }
    __syncthreads();
    bf16x8 af[4], bfr[4];
#pragma unroll
    for (int mt = 0; mt < 4; ++mt) {
      int r = wr + mt * 16 + r15;
      af[mt] = ld8(&As[r * 32 + ((kq ^ (r15 & 3)) * 8)]);
    }
#pragma unroll
    for (int nt = 0; nt < 4; ++nt) {
      int r = wc + nt * 16 + r15;
      bfr[nt] = ld8(&Bs[r * 32 + ((kq ^ (r15 & 3)) * 8)]);
    }
#pragma unroll
    for (int mt = 0; mt < 4; ++mt)
#pragma unroll
      for (int nt = 0; nt < 4; ++nt)
        acc[mt][nt] = __builtin_amdgcn_mfma_f32_16x16x32_bf16(af[mt], bfr[nt], acc[mt][nt], 0, 0, 0);
    __syncthreads();
  }

  if constexpr (MODE == 2) {
    // transpose epilogue: stage C-tile to LDS [col][136], write Vt coalesced
#pragma unroll
    for (int mt = 0; mt < 4; ++mt)
#pragma unroll
      for (int nt = 0; nt < 4; ++nt) {
        int col = wc + nt * 16 + r15;
        float bv = bias[n0 + col];
#pragma unroll
        for (int r = 0; r < 4; ++r) {
          int row = wr + mt * 16 + kq * 4 + r;
          sh[col * 136 + row] = f2bf(acc[mt][nt][r] + bv);
        }
      }
    __syncthreads();
    const int m0l = m0 & 2047;
    const int bb = m0 >> 11;
#pragma unroll
    for (int i = 0; i < 8; ++i) {
      int c = i * 256 + tid;
      int cc = c >> 4, so = c & 15;
      *(uint4*)&Cb[(size_t)(bb * 512 + n0 + cc) * 2048 + m0l + so * 8] =
          *(const uint4*)&sh[cc * 136 + so * 8];
    }
  } else {
    const int rb = kq * 4;
#pragma unroll
    for (int mt = 0; mt < 4; ++mt) {
#pragma unroll
      for (int nt = 0; nt < 4; ++nt) {
        int col = n0 + wc + nt * 16 + r15;
        float bv = bias[col];
#pragma unroll
        for (int r = 0; r < 4; ++r) {
          int row = m0 + wr + mt * 16 + rb + r;
          float v = acc[mt][nt][r] + bv;
          if constexpr (MODE == 0) Cb[(size_t)row * N + col] = f2bf(v);
          else                     Cf[(size_t)row * N + col] = v;
        }
      }
    }
  }
}

// ---------------- fused attention (R3) ----------------
// Block 1024 thr = 16 waves: wave w -> (g = w&7, zz = w>>3).
// QK: wave (g,zz) computes A-tiles [4 heads of g x 4 q] x K[k-half zz].
// PV: wave (g,zz) computes nt-half zz for all 4 heads x 16 q.
__global__ __launch_bounds__(1024, 4)
void attn_fused(const u16* __restrict__ Q, const u16* __restrict__ Kg,
                const u16* __restrict__ Vt, u16* __restrict__ O) {
  __shared__ float slab[8 * 528];  // [g][q*33 + k] partial (4-head) sums
  __shared__ float rsb[528];       // [q*33 + k] 1/sum over 32 heads
  __shared__ u16 Pl[8 * 2592];     // [g][pp*1296 + qh*648 + row*40 + k]

  const int tid = threadIdx.x;
  const int lane = tid & 63, w = tid >> 6;
  const int g = w & 7, zz = w >> 3;
  const int l15 = lane & 15, kq = lane >> 4;

  // XCD pinning: batch b -> 4 XCDs so K[b]+Vt[b] (4MB) fits one XCD L2
  const int xcd = blockIdx.x & 7;
  const int b = xcd >> 2;
  const int q0 = (((blockIdx.x >> 3) << 2) + (xcd & 3)) << 4;

  const u16* Qb = Q + (size_t)b * 2048 * 2048;
  const u16* Kb = Kg + (size_t)b * 2048 * 512;
  const u16* Vb = Vt + (size_t)b * 512 * 2048;

  // hoisted Q fragments: A[row=l15][d]: row = hl*4+qr -> hl=l15>>2, qr=l15&3
  bf16x8 qf[4][2];
#pragma unroll
  for (int qq = 0; qq < 4; ++qq)
#pragma unroll
    for (int t = 0; t < 2; ++t)
      qf[qq][t] = ld8(&Qb[(size_t)(q0 + qq * 4 + (l15 & 3)) * 2048 +
                          (g + 8 * (l15 >> 2)) * 64 + t * 32 + kq * 8]);

  f32x4 acc[2][2][2] = {};  // [pp][qh][ntl]

  for (int k0 = 0; k0 < 2048; k0 += 32) {
    // ---- QK: K direct from global (wave reads its (g, k-half) slice) ----
    const u16* krow = &Kb[(size_t)(k0 + zz * 16 + l15) * 512 + g * 64 + kq * 8];
    bf16x8 bk0 = ld8(krow);
    bf16x8 bk1 = ld8(krow + 32);
    u32 epk[4][2];
    f32x4 su[4];
#pragma unroll
    for (int qq = 0; qq < 4; ++qq) {
      f32x4 s = {};
      s = __builtin_amdgcn_mfma_f32_16x16x32_bf16(qf[qq][0], bk0, s, 0, 0, 0);
      s = __builtin_amdgcn_mfma_f32_16x16x32_bf16(qf[qq][1], bk1, s, 0, 0, 0);
      float e0 = __expf(s[0] * 0.125f);
      float e1 = __expf(s[1] * 0.125f);
      float e2 = __expf(s[2] * 0.125f);
      float e3 = __expf(s[3] * 0.125f);
      epk[qq][0] = __builtin_amdgcn_perm(__float_as_uint(e1), __float_as_uint(e0), 0x07060302u);
      epk[qq][1] = __builtin_amdgcn_perm(__float_as_uint(e3), __float_as_uint(e2), 0x07060302u);
      f32x4 t = {e0, e1, e2, e3};
#pragma unroll
      for (int c = 0; c < 4; ++c) {
        t[c] += __shfl_xor(t[c], 16);  // sum across head quarters
        t[c] += __shfl_xor(t[c], 32);
      }
      su[qq] = t;
    }
    // quarter kq writes q-quad qq=kq (sums are quarter-replicated)
#pragma unroll
    for (int r = 0; r < 4; ++r) {
      float v = kq == 0 ? su[0][r] : kq == 1 ? su[1][r] : kq == 2 ? su[2][r] : su[3][r];
      slab[g * 528 + (kq * 4 + r) * 33 + zz * 16 + l15] = v;
    }
    __syncthreads();  // B_A

    // ---- reduce over 8 groups ----
    if (tid < 512) {
      int q = tid >> 5, k = tid & 31;
      float s = 0.f;
#pragma unroll
      for (int gg = 0; gg < 8; ++gg) s += slab[gg * 528 + q * 33 + k];
      rsb[q * 33 + k] = __builtin_amdgcn_rcpf(s);
    }
    __syncthreads();  // B_B

    // ---- P = e * rs -> bf16 into Pl [g][pp][qh][row16][40] ----
#pragma unroll
    for (int qq = 0; qq < 4; ++qq) {
      float rsv[4];
#pragma unroll
      for (int r = 0; r < 4; ++r) rsv[r] = rsb[(qq * 4 + r) * 33 + zz * 16 + l15];
      u32 lo = epk[qq][0], hi = epk[qq][1];
      float p0 = __uint_as_float(lo << 16) * rsv[0];
      float p1 = __uint_as_float(lo & 0xffff0000u) * rsv[1];
      float p2 = __uint_as_float(hi << 16) * rsv[2];
      float p3 = __uint_as_float(hi & 0xffff0000u) * rsv[3];
      int base = g * 2592 + (kq >> 1) * 1296 + (qq >> 1) * 648 +
                 ((kq & 1) * 8 + (qq & 1) * 4) * 40 + zz * 16 + l15;
      Pl[base + 0 * 40] = f2bf(p0);
      Pl[base + 1 * 40] = f2bf(p1);
      Pl[base + 2 * 40] = f2bf(p2);
      Pl[base + 3 * 40] = f2bf(p3);
    }
    __syncthreads();  // B_C

    // ---- PV: P b128 from LDS, Vt direct from global (nt-half zz) ----
    bf16x8 vb[2];
#pragma unroll
    for (int nl = 0; nl < 2; ++nl)
      vb[nl] = ld8(&Vb[(size_t)(g * 64 + (zz * 2 + nl) * 16 + l15) * 2048 + k0 + kq * 8]);
#pragma unroll
    for (int pp = 0; pp < 2; ++pp)
#pragma unroll
      for (int qh = 0; qh < 2; ++qh) {
        bf16x8 pa = ld8(&Pl[g * 2592 + pp * 1296 + qh * 648 + l15 * 40 + kq * 8]);
#pragma unroll
        for (int nl = 0; nl < 2; ++nl)
          acc[pp][qh][nl] =
              __builtin_amdgcn_mfma_f32_16x16x32_bf16(pa, vb[nl], acc[pp][qh][nl], 0, 0, 0);
      }
    // no trailing barrier needed: next write to Pl is 2 barriers away
  }

  // ---- epilogue ----
#pragma unroll
  for (int pp = 0; pp < 2; ++pp)
#pragma unroll
    for (int qh = 0; qh < 2; ++qh)
#pragma unroll
      for (int nl = 0; nl < 2; ++nl)
#pragma unroll
        for (int r = 0; r < 4; ++r) {
          int q = q0 + qh * 8 + (kq & 1) * 4 + r;
          int h = g + 8 * (2 * pp + (kq >> 1));
          O[((size_t)(b * 2048 + q)) * 2048 + h * 64 + (zz * 2 + nl) * 16 + l15] =
              f2bf(acc[pp][qh][nl][r]);
        }
}

// ---------------- launcher ----------------
extern "C" void kernel_launch(void* const* d_in, const int* in_sizes, int n_in,
                              void* d_out, int out_size, void* d_ws, size_t ws_size,
                              hipStream_t stream) {
  (void)in_sizes; (void)n_in; (void)out_size; (void)ws_size;
  const float* x    = (const float*)d_in[0];
  const float* wq_w = (const float*)d_in[1];
  const float* wq_b = (const float*)d_in[2];
  const float* wk_w = (const float*)d_in[3];
  const float* wk_b = (const float*)d_in[4];
  const float* wv_w = (const float*)d_in[5];
  const float* wv_b = (const float*)d_in[6];
  const float* wo_w = (const float*)d_in[7];
  const float* wo_b = (const float*)d_in[8];
  float* out = (float*)d_out;

  char* p = (char*)d_ws;
  u16* xb  = (u16*)p; p += (size_t)4096 * 2048 * 2;
  u16* wqb = (u16*)p; p += (size_t)2048 * 2048 * 2;
  u16* wkb = (u16*)p; p += (size_t)512 * 2048 * 2;
  u16* wvb = (u16*)p; p += (size_t)512 * 2048 * 2;
  u16* wob = (u16*)p; p += (size_t)2048 * 2048 * 2;
  u16* Qb  = (u16*)p; p += (size_t)4096 * 2048 * 2;
  u16* Kb  = (u16*)p; p += (size_t)4096 * 512 * 2;
  u16* Vtb = (u16*)p; p += (size_t)1024 * 2048 * 2;   // [b*512+d][s]
  u16* Ob  = (u16*)p; p += (size_t)4096 * 2048 * 2;

  auto cvt = [&](const float* in, u16* o, int n) {
    int n8 = n / 8;
    int grid = (n8 + 255) / 256; if (grid > 2048) grid = 2048;
    hipLaunchKernelGGL(cvt_bf16, dim3(grid), dim3(256), 0, stream, in, o, n8);
  };
  cvt(x, xb, 4096 * 2048);
  cvt(wq_w, wqb, 2048 * 2048);
  cvt(wk_w, wkb, 512 * 2048);
  cvt(wv_w, wvb, 512 * 2048);
  cvt(wo_w, wob, 2048 * 2048);

  hipLaunchKernelGGL((gemm_bt<0>), dim3(16, 32), dim3(256), 0, stream,
                     xb, wqb, wq_b, Qb, (float*)nullptr, 2048);
  hipLaunchKernelGGL((gemm_bt<0>), dim3(4, 32),  dim3(256), 0, stream,
                     xb, wkb, wk_b, Kb, (float*)nullptr, 512);
  hipLaunchKernelGGL((gemm_bt<2>), dim3(4, 32),  dim3(256), 0, stream,
                     xb, wvb, wv_b, Vtb, (float*)nullptr, 512);

  hipLaunchKernelGGL(attn_fused, dim3(256), dim3(1024), 0, stream, Qb, Kb, Vtb, Ob);

  hipLaunchKernelGGL((gemm_bt<1>), dim3(16, 32), dim3(256), 0, stream,
                     Ob, wob, wo_b, (u16*)nullptr, out, 2048);
}

// Round 4
// 447.989 us; speedup vs baseline: 2.3735x; 1.0314x over previous
//
#include <hip/hip_runtime.h>

// GQA (B=2,S=2048,E=2048,H=32,G=8,D=64), softmax over HEAD axis.
// R4: swapped-operand QK (mfma(K,Q)) puts P in registers in exactly PV's
// A-frag layout -> no P LDS round-trip. Head-sum: 2x DPP row_ror adds
// (intra-wave, 4 heads of g) + 8-way cross-g LDS slab reduce (2 barriers).
// V read direct from global in k-interleaved Vt2 layout (one b128 B-frag),
// produced by V-proj GEMM epilogue. 16 waves = 8g x 2 q-halves.

typedef unsigned short u16;
typedef unsigned int u32;
typedef __attribute__((ext_vector_type(8))) __bf16 bf16x8;
typedef __attribute__((ext_vector_type(4))) float f32x4;
typedef __attribute__((ext_vector_type(4))) float float4_t;

#define GLD16(ldsp, gp)                                                  \
  __builtin_amdgcn_global_load_lds(                                      \
      (__attribute__((address_space(1))) void*)(void*)(gp),              \
      (__attribute__((address_space(3))) void*)(void*)(ldsp), 16, 0, 0)

static __device__ __forceinline__ u16 f2bf(float f) {
  union { float f; u32 u; } v; v.f = f;
  u32 u = v.u;
  u32 r = (u + 0x7fffu + ((u >> 16) & 1u)) >> 16;  // RNE
  return (u16)r;
}

static __device__ __forceinline__ bf16x8 ld8(const u16* p) {
  return *(const bf16x8*)p;
}

// sum over the 4 stride-4 lanes within each 16-lane row (head levels)
static __device__ __forceinline__ float hsum4(float v) {
  v += __builtin_bit_cast(float, __builtin_amdgcn_update_dpp(
           0, __builtin_bit_cast(int, v), 0x124, 0xf, 0xf, true));  // row_ror:4
  v += __builtin_bit_cast(float, __builtin_amdgcn_update_dpp(
           0, __builtin_bit_cast(int, v), 0x128, 0xf, 0xf, true));  // row_ror:8
  return v;
}

// ---------------- fp32 -> bf16 ----------------
__global__ void cvt_bf16(const float* __restrict__ in, u16* __restrict__ out, int n8) {
  int i = blockIdx.x * blockDim.x + threadIdx.x;
  int stride = gridDim.x * blockDim.x;
  for (; i < n8; i += stride) {
    const float4_t* p = (const float4_t*)in + (size_t)i * 2;
    float4_t a = p[0], b = p[1];
    u32 w0 = (u32)f2bf(a[0]) | ((u32)f2bf(a[1]) << 16);
    u32 w1 = (u32)f2bf(a[2]) | ((u32)f2bf(a[3]) << 16);
    u32 w2 = (u32)f2bf(b[0]) | ((u32)f2bf(b[1]) << 16);
    u32 w3 = (u32)f2bf(b[2]) | ((u32)f2bf(b[3]) << 16);
    *(uint4*)(out + (size_t)i * 8) = make_uint4(w0, w1, w2, w3);
  }
}

// ---------------- GEMM: C[M,N] = A[M,K] @ W[N,K]^T + bias ----------------
// MODE 0: bf16 row-major; 1: f32 row-major; 2: bf16 transposed per-batch
// Vt2[b*512+col][s] with k-interleave within each 32-s block:
//   position kq*8+j holds V[s = 32blk + kq*4 + (j>>1) + 16*(j&1)].
template <int MODE>
__global__ __launch_bounds__(256, 2)
void gemm_bt(const u16* __restrict__ A, const u16* __restrict__ Bw,
             const float* __restrict__ bias,
             u16* __restrict__ Cb, float* __restrict__ Cf, int N) {
  constexpr int K = 2048;
  constexpr int SHSZ = (MODE == 2) ? (128 * 136) : 8192;
  __shared__ u16 sh[SHSZ];
  u16* As = sh;
  u16* Bs = sh + 4096;
  const int tid = threadIdx.x;
  const int lane = tid & 63;
  const int w = tid >> 6;
  const int m0 = blockIdx.y * 128;
  const int n0 = blockIdx.x * 128;
  const int wr = (w >> 1) * 64, wc = (w & 1) * 64;
  const int r15 = lane & 15, kq = lane >> 4;

  f32x4 acc[4][4] = {};

  for (int k0 = 0; k0 < K; k0 += 32) {
#pragma unroll
    for (int i = 0; i < 2; ++i) {
      int c = i * 256 + tid;
      int r = c >> 2, ch = c & 3;
      int sc = (ch ^ (r & 3)) * 8;
      GLD16(&As[c * 8], &A[(size_t)(m0 + r) * K + k0 + sc]);
      GLD16(&Bs[c * 8], &Bw[(size_t)(n0 + r) * K + k0 + sc]);
    }
    __syncthreads();
    bf16x8 af[4], bfr[4];
#pragma unroll
    for (int mt = 0; mt < 4; ++mt) {
      int r = wr + mt * 16 + r15;
      af[mt] = ld8(&As[r * 32 + ((kq ^ (r15 & 3)) * 8)]);
    }
#pragma unroll
    for (int nt = 0; nt < 4; ++nt) {
      int r = wc + nt * 16 + r15;
      bfr[nt] = ld8(&Bs[r * 32 + ((kq ^ (r15 & 3)) * 8)]);
    }
#pragma unroll
    for (int mt = 0; mt < 4; ++mt)
#pragma unroll
      for (int nt = 0; nt < 4; ++nt)
        acc[mt][nt] = __builtin_amdgcn_mfma_f32_16x16x32_bf16(af[mt], bfr[nt], acc[mt][nt], 0, 0, 0);
    __syncthreads();
  }

  if constexpr (MODE == 2) {
    // transpose epilogue: C-tile -> LDS [col][136], then k-interleaved write
#pragma unroll
    for (int mt = 0; mt < 4; ++mt)
#pragma unroll
      for (int nt = 0; nt < 4; ++nt) {
        int col = wc + nt * 16 + r15;
        float bv = bias[n0 + col];
#pragma unroll
        for (int r = 0; r < 4; ++r) {
          int row = wr + mt * 16 + kq * 4 + r;
          sh[col * 136 + row] = f2bf(acc[mt][nt][r] + bv);
        }
      }
    __syncthreads();
    const int m0l = m0 & 2047;
    const int bb = m0 >> 11;
#pragma unroll
    for (int i = 0; i < 8; ++i) {
      int c = i * 256 + tid;
      int cc = c >> 4, so = c & 15;
      // permuted read: X + {0..3} interleaved with X+16+{0..3}
      int X = cc * 136 + (so >> 2) * 32 + (so & 3) * 4;
      u32 A0 = *(const u32*)&sh[X + 0];
      u32 A1 = *(const u32*)&sh[X + 2];
      u32 B0 = *(const u32*)&sh[X + 16];
      u32 B1 = *(const u32*)&sh[X + 18];
      u32 w0 = __builtin_amdgcn_perm(B0, A0, 0x05040100u);
      u32 w1 = __builtin_amdgcn_perm(B0, A0, 0x07060302u);
      u32 w2 = __builtin_amdgcn_perm(B1, A1, 0x05040100u);
      u32 w3 = __builtin_amdgcn_perm(B1, A1, 0x07060302u);
      *(uint4*)&Cb[(size_t)(bb * 512 + n0 + cc) * 2048 + m0l + so * 8] =
          make_uint4(w0, w1, w2, w3);
    }
  } else {
    const int rb = kq * 4;
#pragma unroll
    for (int mt = 0; mt < 4; ++mt) {
#pragma unroll
      for (int nt = 0; nt < 4; ++nt) {
        int col = n0 + wc + nt * 16 + r15;
        float bv = bias[col];
#pragma unroll
        for (int r = 0; r < 4; ++r) {
          int row = m0 + wr + mt * 16 + rb + r;
          float v = acc[mt][nt][r] + bv;
          if constexpr (MODE == 0) Cb[(size_t)row * N + col] = f2bf(v);
          else                     Cf[(size_t)row * N + col] = v;
        }
      }
    }
  }
}

// ---------------- fused attention (R4) ----------------
// 16 waves = (g = w&7, zd = w>>3); wave covers heads {g,g+8,g+16,g+24},
// q-rows qbase..qbase+7 (zd-half of 16), all 64 d.
// Per 32-k tile: load K/V frags from global (L2); QK = mfma(K,Q) -> lane
// holds P'[k][hq=r15]; exp2; hsum4 over head-levels (DPP); slab write;
// B1; 8-way cross-g reduce -> rsb(1/sum); B2; pack P*rs -> bf16 A-frag;
// PV mfma. P never touches LDS.
__global__ __launch_bounds__(1024, 4)
void attn_fused(const u16* __restrict__ Q, const u16* __restrict__ Kg,
                const u16* __restrict__ Vt, u16* __restrict__ O) {
  __shared__ float slab[8 * 528];  // [g][q*33 + k], q 0..15, k 0..31
  __shared__ float rsb[16 * 36];   // [q][k] 1/sum, row pad 36 (16B align)

  const int tid = threadIdx.x;
  const int lane = tid & 63, w = tid >> 6;
  const int g = w & 7, zd = w >> 3;
  const int l15 = lane & 15, kq = lane >> 4;
  const int qr = l15 & 3, hl = l15 >> 2;

  // XCD pinning: batch b -> 4 XCDs so K[b]+Vt[b] (4MB) stays in L2
  const int xcd = blockIdx.x & 7;
  const int b = xcd >> 2;
  const int q0 = ((((blockIdx.x >> 3) << 2) + (xcd & 3)) << 4);
  const int qbase = q0 + zd * 8;

  const u16* Qb = Q + (size_t)b * 2048 * 2048;
  const u16* Kb = Kg + (size_t)b * 2048 * 512;
  const u16* Vb = Vt + (size_t)b * 512 * 2048;  // k-interleaved Vt2

  // Q B-frags: lane r15 = (hl,qr) col, elements = d
  bf16x8 qf[2][2];
#pragma unroll
  for (int qq = 0; qq < 2; ++qq)
#pragma unroll
    for (int t = 0; t < 2; ++t)
      qf[qq][t] = ld8(&Qb[(size_t)(qbase + qq * 4 + qr) * 2048 +
                          (g + 8 * hl) * 64 + t * 32 + kq * 8]);

  f32x4 acc[2][4] = {};  // [qq][nt]

  for (int k0 = 0; k0 < 2048; k0 += 32) {
    // ---- K A-frags: lane l15 = k-row ----
    bf16x8 kf[2][2];
#pragma unroll
    for (int ko = 0; ko < 2; ++ko)
#pragma unroll
      for (int t = 0; t < 2; ++t)
        kf[ko][t] = ld8(&Kb[(size_t)(k0 + ko * 16 + l15) * 512 +
                            g * 64 + t * 32 + kq * 8]);

    // ---- QK^T (swapped): sc[qq][ko] -> P'[k = kq*4+reg][hq = r15] ----
    f32x4 sc[2][2];
#pragma unroll
    for (int qq = 0; qq < 2; ++qq)
#pragma unroll
      for (int ko = 0; ko < 2; ++ko) {
        f32x4 s = {};
        s = __builtin_amdgcn_mfma_f32_16x16x32_bf16(kf[ko][0], qf[qq][0], s, 0, 0, 0);
        s = __builtin_amdgcn_mfma_f32_16x16x32_bf16(kf[ko][1], qf[qq][1], s, 0, 0, 0);
        // exp(s/8) == exp2(s * 0.125*log2e), exact rewrite
#pragma unroll
        for (int r = 0; r < 4; ++r) s[r] = exp2f(s[r] * 0.18033688f);
        sc[qq][ko] = s;
      }

    // ---- intra-wave 4-head sums (DPP) + slab write ----
#pragma unroll
    for (int qq = 0; qq < 2; ++qq)
#pragma unroll
      for (int ko = 0; ko < 2; ++ko) {
#pragma unroll
        for (int r = 0; r < 4; ++r) {
          float su = hsum4(sc[qq][ko][r]);
          if (hl == 0)
            slab[g * 528 + (zd * 8 + qq * 4 + qr) * 33 + ko * 16 + kq * 4 + r] = su;
        }
      }

    // ---- V B-frags (issue early; consumed after B2) ----
    bf16x8 vb[4];
#pragma unroll
    for (int nt = 0; nt < 4; ++nt)
      vb[nt] = ld8(&Vb[(size_t)(g * 64 + nt * 16 + l15) * 2048 + k0 + kq * 8]);

    __syncthreads();  // B1

    // ---- cross-g reduce: 1/sum over all 32 heads ----
    if (tid < 512) {
      int q = tid >> 5, k = tid & 31;
      float s = 0.f;
#pragma unroll
      for (int gg = 0; gg < 8; ++gg) s += slab[gg * 528 + q * 33 + k];
      rsb[q * 36 + k] = __builtin_amdgcn_rcpf(s);
    }
    __syncthreads();  // B2

    // ---- P = e * rs, pack as PV A-frag (k-interleaved), PV mfma ----
#pragma unroll
    for (int qq = 0; qq < 2; ++qq) {
      const int ql = zd * 8 + qq * 4 + qr;
      f32x4 rs0 = *(const f32x4*)&rsb[ql * 36 + 0 * 16 + kq * 4];
      f32x4 rs1 = *(const f32x4*)&rsb[ql * 36 + 1 * 16 + kq * 4];
      u32 paw[4];
#pragma unroll
      for (int r = 0; r < 4; ++r)
        paw[r] = (u32)f2bf(sc[qq][0][r] * rs0[r]) |
                 ((u32)f2bf(sc[qq][1][r] * rs1[r]) << 16);
      bf16x8 pa = __builtin_bit_cast(bf16x8, *(uint4*)paw);
#pragma unroll
      for (int nt = 0; nt < 4; ++nt)
        acc[qq][nt] = __builtin_amdgcn_mfma_f32_16x16x32_bf16(pa, vb[nt], acc[qq][nt], 0, 0, 0);
    }
  }

  // ---- epilogue: D row = kq*4+reg -> (h-level = kq, q-row = reg) ----
#pragma unroll
  for (int qq = 0; qq < 2; ++qq)
#pragma unroll
    for (int nt = 0; nt < 4; ++nt)
#pragma unroll
      for (int r = 0; r < 4; ++r)
        O[(size_t)(b * 2048 + qbase + qq * 4 + r) * 2048 +
          (g + 8 * kq) * 64 + nt * 16 + l15] = f2bf(acc[qq][nt][r]);
}

// ---------------- launcher ----------------
extern "C" void kernel_launch(void* const* d_in, const int* in_sizes, int n_in,
                              void* d_out, int out_size, void* d_ws, size_t ws_size,
                              hipStream_t stream) {
  (void)in_sizes; (void)n_in; (void)out_size; (void)ws_size;
  const float* x    = (const float*)d_in[0];
  const float* wq_w = (const float*)d_in[1];
  const float* wq_b = (const float*)d_in[2];
  const float* wk_w = (const float*)d_in[3];
  const float* wk_b = (const float*)d_in[4];
  const float* wv_w = (const float*)d_in[5];
  const float* wv_b = (const float*)d_in[6];
  const float* wo_w = (const float*)d_in[7];
  const float* wo_b = (const float*)d_in[8];
  float* out = (float*)d_out;

  char* p = (char*)d_ws;
  u16* xb  = (u16*)p; p += (size_t)4096 * 2048 * 2;
  u16* wqb = (u16*)p; p += (size_t)2048 * 2048 * 2;
  u16* wkb = (u16*)p; p += (size_t)512 * 2048 * 2;
  u16* wvb = (u16*)p; p += (size_t)512 * 2048 * 2;
  u16* wob = (u16*)p; p += (size_t)2048 * 2048 * 2;
  u16* Qb  = (u16*)p; p += (size_t)4096 * 2048 * 2;
  u16* Kb  = (u16*)p; p += (size_t)4096 * 512 * 2;
  u16* Vtb = (u16*)p; p += (size_t)1024 * 2048 * 2;   // Vt2 [b*512+d][s-perm]
  u16* Ob  = (u16*)p; p += (size_t)4096 * 2048 * 2;

  auto cvt = [&](const float* in, u16* o, int n) {
    int n8 = n / 8;
    int grid = (n8 + 255) / 256; if (grid > 2048) grid = 2048;
    hipLaunchKernelGGL(cvt_bf16, dim3(grid), dim3(256), 0, stream, in, o, n8);
  };
  cvt(x, xb, 4096 * 2048);
  cvt(wq_w, wqb, 2048 * 2048);
  cvt(wk_w, wkb, 512 * 2048);
  cvt(wv_w, wvb, 512 * 2048);
  cvt(wo_w, wob, 2048 * 2048);

  hipLaunchKernelGGL((gemm_bt<0>), dim3(16, 32), dim3(256), 0, stream,
                     xb, wqb, wq_b, Qb, (float*)nullptr, 2048);
  hipLaunchKernelGGL((gemm_bt<0>), dim3(4, 32),  dim3(256), 0, stream,
                     xb, wkb, wk_b, Kb, (float*)nullptr, 512);
  hipLaunchKernelGGL((gemm_bt<2>), dim3(4, 32),  dim3(256), 0, stream,
                     xb, wvb, wv_b, Vtb, (float*)nullptr, 512);

  hipLaunchKernelGGL(attn_fused, dim3(256), dim3(1024), 0, stream, Qb, Kb, Vtb, Ob);

  hipLaunchKernelGGL((gemm_bt<1>), dim3(16, 32), dim3(256), 0, stream,
                     Ob, wob, wo_b, (u16*)nullptr, out, 2048);
}